// Round 2
// baseline (202.290 us; speedup 1.0000x reference)
//
#include <hip/hip_runtime.h>
#include <math.h>

// Problem constants (fixed by setup_inputs): B=32, S=64, H=256.
#define EPSF 1e-8f
constexpr int B = 32;
constexpr int S = 64;
constexpr int H = 256;                 // floats per cell
constexpr int H4 = H / 4;              // float4 per cell = 64 (one per lane)
constexpr int CELLS_PER_BATCH = S * S; // 4096
constexpr int CELLS = B * CELLS_PER_BATCH; // 131072
constexpr int CELLS_PER_WAVE = 16;
constexpr int WAVES_PER_BLOCK = 4;     // 256 threads
constexpr int CELLS_PER_BLOCK = CELLS_PER_WAVE * WAVES_PER_BLOCK; // 64
constexpr int NBLK = CELLS / CELLS_PER_BLOCK;                     // 2048
constexpr int BLOCKS_PER_BATCH = NBLK / B;                        // 64

// ws layout (floats): per-block partials, no atomics, no pre-zero needed:
//   ws[blk*2]   = sum exp(pos)   for block blk
//   ws[blk*2+1] = sum exp(neg)

// ---------------- kernel 1: main pass over all (b,i,j) cells ----------------
__global__ __launch_bounds__(256) void main_kernel(const float* __restrict__ tmap,
                                                   const float* __restrict__ pq,
                                                   const int* __restrict__ mask_pos,
                                                   const int* __restrict__ mask_neg,
                                                   float* __restrict__ ws) {
    int tid = threadIdx.x;
    int lane = tid & 63;
    int wid = tid >> 6;
    int cellBase = blockIdx.x * CELLS_PER_BLOCK + wid * CELLS_PER_WAVE;
    int b = cellBase >> 12;  // / CELLS_PER_BATCH; block never straddles a batch

    // q-norm fused per wave (once per 16 cells — cheap)
    float4 q4 = ((const float4*)pq)[b * H4 + lane];
    float qss = q4.x * q4.x + q4.y * q4.y + q4.z * q4.z + q4.w * q4.w;
    #pragma unroll
    for (int off = 32; off > 0; off >>= 1) qss += __shfl_xor(qss, off);
    // s = dot(t,q) / (||t||(1+eps)) / (||q||+eps)
    float scale = (1.0f / (sqrtf(qss) + EPSF)) * (1.0f / (1.0f + EPSF));

    // vectorized mask loads: 16 cells -> 4 int4 each (cellBase % 16 == 0)
    int mp[CELLS_PER_WAVE], mn[CELLS_PER_WAVE];
    #pragma unroll
    for (int v = 0; v < CELLS_PER_WAVE / 4; ++v) {
        int4 a = ((const int4*)(mask_pos + cellBase))[v];
        int4 c = ((const int4*)(mask_neg + cellBase))[v];
        mp[v*4+0] = a.x; mp[v*4+1] = a.y; mp[v*4+2] = a.z; mp[v*4+3] = a.w;
        mn[v*4+0] = c.x; mn[v*4+1] = c.y; mn[v*4+2] = c.z; mn[v*4+3] = c.w;
    }

    float wp = 0.0f, wn = 0.0f;
    #pragma unroll
    for (int k = 0; k < CELLS_PER_WAVE; ++k) {
        int cell = cellBase + k;
        float4 t = ((const float4*)tmap)[cell * H4 + lane];
        float d  = t.x * q4.x + t.y * q4.y + t.z * q4.z + t.w * q4.w;
        float ss = t.x * t.x + t.y * t.y + t.z * t.z + t.w * t.w;
        #pragma unroll
        for (int off = 32; off > 0; off >>= 1) {
            d  += __shfl_xor(d, off);
            ss += __shfl_xor(ss, off);
        }
        float s = d * scale * rsqrtf(ss);
        float e = __expf(s);  // TAO = 1
        if (mp[k] != 0) wp += e;
        if (mn[k] != 0) wn += e;
    }

    __shared__ float sp[WAVES_PER_BLOCK], sn[WAVES_PER_BLOCK];
    if (lane == 0) { sp[wid] = wp; sn[wid] = wn; }
    __syncthreads();
    if (tid == 0) {
        float tp = 0.0f, tn = 0.0f;
        #pragma unroll
        for (int w = 0; w < WAVES_PER_BLOCK; ++w) { tp += sp[w]; tn += sn[w]; }
        ws[blockIdx.x * 2]     = tp;   // own slot: no atomic, no pre-zero
        ws[blockIdx.x * 2 + 1] = tn;
    }
}

// ---------------- kernel 2: reduce partials, per-batch loss, average ----------------
__global__ __launch_bounds__(256) void final_kernel(const float* __restrict__ ws,
                                                    float* __restrict__ out) {
    int tid = threadIdx.x;           // 256 threads; 8 threads per batch
    int batch = tid >> 3;            // 0..31
    int sub = tid & 7;

    float ep = 0.0f, en = 0.0f;
    #pragma unroll
    for (int j = 0; j < BLOCKS_PER_BATCH / 8; ++j) {   // 8 pairs per thread
        int blk = batch * BLOCKS_PER_BATCH + sub * (BLOCKS_PER_BATCH / 8) + j;
        ep += ws[blk * 2];
        en += ws[blk * 2 + 1];
    }
    // reduce the 8 subthreads of each batch (contiguous lanes within a wave)
    #pragma unroll
    for (int off = 1; off < 8; off <<= 1) {
        ep += __shfl_xor(ep, off);
        en += __shfl_xor(en, off);
    }

    __shared__ float lli[B];
    __shared__ int   lv[B];
    if (sub == 0) {
        int v = 0; float li = 0.0f;
        if (ep > 0.0f && en > 0.0f) {   // == any(mask_pos)&&any(mask_neg): exp>0
            v = 1;
            li = -logf(ep / (ep + en + EPSF));
        }
        lli[batch] = li; lv[batch] = v;
    }
    __syncthreads();
    if (tid < 64) {
        float li = (tid < B) ? lli[tid] : 0.0f;
        int   v  = (tid < B) ? lv[tid]  : 0;
        #pragma unroll
        for (int off = 32; off > 0; off >>= 1) {
            li += __shfl_xor(li, off);
            v  += __shfl_xor(v, off);
        }
        if (tid == 0) out[0] = li / (float)(v > 0 ? v : 1);
    }
}

extern "C" void kernel_launch(void* const* d_in, const int* in_sizes, int n_in,
                              void* d_out, int out_size, void* d_ws, size_t ws_size,
                              hipStream_t stream) {
    const float* pos_query = (const float*)d_in[0];  // (B,H) fp32
    const float* tmap      = (const float*)d_in[1];  // (B,S,S,H) fp32
    const int*   mask_pos  = (const int*)d_in[2];    // (B,S,S) bool -> int32
    const int*   mask_neg  = (const int*)d_in[3];
    float* out = (float*)d_out;
    float* ws  = (float*)d_ws;

    main_kernel<<<NBLK, 256, 0, stream>>>(tmap, pos_query, mask_pos, mask_neg, ws);
    final_kernel<<<1, 256, 0, stream>>>(ws, out);
}